// Round 6
// baseline (954.632 us; speedup 1.0000x reference)
//
#include <hip/hip_runtime.h>

// BinarizeLayer forward (r6: producer/streamer split):
//   A (producer): coalesced cont load -> LDS(17), bit-faithful soft-bin math,
//                 pack 16x 8-bit indices per row into one uint4 -> d_ws (8.4 MB),
//                 per-block loss partial -> d_ws. No disc, no one-hot stores.
//   B (streamer): per block load 256 uint4 idx + disc sectors -> LDS (22.5 KB),
//                 then 100 fully-coalesced float4 stores per row-tile -- a pure
//                 write stream shaped like fillBufferAligned (6.25 TB/s measured).
//   finalize   : reduce 2048 partials, write loss scalar.
// Fallback (ws too small): proven fused r3-style kernel.

typedef float vfloat4 __attribute__((ext_vector_type(4)));

constexpr int kB      = 524288;
constexpr int kF      = 16;
constexpr int kK1     = 16;
constexpr int kK2     = 8;
constexpr int kRowIn  = 32;    // DISC + F
constexpr int kRowOut = 400;   // DISC + F*K1 + F*K2
constexpr float kEps  = 0.001f;
constexpr int kTPB    = 256;   // threads per block == rows per block
constexpr int kGrid   = kB / kTPB;     // 2048 blocks
constexpr int kXStride = 17;   // LDS float row stride
constexpr int kWStride = 5;    // LDS uint row stride for packed idx

template <int K>
__device__ __forceinline__ int soft_argmax_loss(const float* __restrict__ dd,
                                                double& lacc)
{
#pragma clang fp contract(off)
    // loss term: sum_k d*softmax(-d); fast exp (output threshold-checked)
    float se = 0.f, sde = 0.f;
#pragma unroll
    for (int k = 0; k < K; ++k) {
        float e = __expf(-dd[k]);
        se += e; sde += dd[k] * e;
    }
    lacc += (double)(sde / se);

    // argmax(softmax(-100*d)) fast path: first-occurrence argmax of z
    float z[K];
#pragma unroll
    for (int k = 0; k < K; ++k) z[k] = -100.0f * dd[k];
    float m = z[0]; int kmax = 0;
#pragma unroll
    for (int k = 1; k < K; ++k) {
        if (z[k] > m) { m = z[k]; kmax = k; }
    }
    // tie-guard: exact expf+IEEE-div replication only if an earlier z is
    // within ~1 ulp of m (exec-masked, ~never taken). Bit-faithful to numpy.
    bool cand = false;
#pragma unroll
    for (int k = 0; k < K; ++k)
        cand |= (k < kmax) & (z[k] >= m - 2.4e-7f);
    if (cand) {
        float e2[K]; float ss = 0.f;
        for (int k = 0; k < K; ++k) { e2[k] = expf(z[k] - m); ss += e2[k]; }
        int km = 0; float pmax = e2[0] / ss;
        for (int k = 1; k < K; ++k) {
            float p = e2[k] / ss;
            if (p > pmax) { pmax = p; km = k; }
        }
        kmax = km;
    }
    return kmax;
}

__device__ __forceinline__ void load_centers(
    const float* __restrict__ interval, const float* __restrict__ interval2,
    const float* __restrict__ i_min, int tid,
    float (*sC1)[kK1], float (*sC2)[kK2])
{
#pragma clang fp contract(off)
    if (tid < kF) {
        const float base = i_min[tid];
        float run = 0.f;
        for (int k = 0; k < kK1; ++k) {
            run += fmaxf(interval[tid * kK1 + k], kEps);
            sC1[tid][k] = base + run;
        }
        run = 0.f;
        for (int k = 0; k < kK2; ++k) {
            run += fmaxf(interval2[tid * kK2 + k], kEps);
            sC2[tid][k] = base + run;
        }
    }
}

// ======================= producer =======================
__global__ __launch_bounds__(kTPB) void binlayer_compute(
    const float* __restrict__ x,
    const float* __restrict__ interval,
    const float* __restrict__ interval2,
    const float* __restrict__ i_min,
    uint4* __restrict__ idxbuf,
    double* __restrict__ partial)
{
#pragma clang fp contract(off)
    __shared__ float sC1[kF][kK1];
    __shared__ float sC2[kF][kK2];
    __shared__ float sCont[kTPB * kXStride];
    __shared__ double sL[kTPB / 64];

    const int tid = threadIdx.x;
    load_centers(interval, interval2, i_min, tid, sC1, sC2);

    const long long rowBase = (long long)blockIdx.x * kTPB;
    const vfloat4* __restrict__ xin4 = (const vfloat4*)(x + rowBase * kRowIn);

    // cont halves -> LDS (chunks 4..7 of each 8-chunk row)
#pragma unroll
    for (int i = 0; i < 4; ++i) {
        int flat = i * kTPB + tid;
        int r = flat >> 2, c = flat & 3;
        vfloat4 v = xin4[r * 8 + 4 + c];
        float* p = &sCont[r * kXStride + c * 4];
        p[0] = v.x; p[1] = v.y; p[2] = v.z; p[3] = v.w;
    }
    __syncthreads();

    double lacc = 0.0;
    const float* __restrict__ myc = &sCont[tid * kXStride];
    unsigned w[4] = {0u, 0u, 0u, 0u};

#pragma unroll 1
    for (int f = 0; f < kF; ++f) {
        const float c = myc[f];
        float dd1[kK1];
#pragma unroll
        for (int k = 0; k < kK1; ++k) { float t = c - sC1[f][k]; dd1[k] = t * t; }
        int k1 = soft_argmax_loss<kK1>(dd1, lacc);
        float dd2[kK2];
#pragma unroll
        for (int k = 0; k < kK2; ++k) { float t = c - sC2[f][k]; dd2[k] = t * t; }
        int k2 = soft_argmax_loss<kK2>(dd2, lacc);
        w[f >> 2] |= (unsigned)(k1 | (k2 << 4)) << (8 * (f & 3));
    }

    idxbuf[rowBase + tid] = make_uint4(w[0], w[1], w[2], w[3]);

#pragma unroll
    for (int off = 32; off > 0; off >>= 1) lacc += __shfl_down(lacc, off);
    if ((tid & 63) == 0) sL[tid >> 6] = lacc;
    __syncthreads();
    if (tid == 0) partial[blockIdx.x] = sL[0] + sL[1] + sL[2] + sL[3];
}

// ======================= streamer =======================
__global__ __launch_bounds__(kTPB) void binlayer_expand(
    const float* __restrict__ x,
    const uint4* __restrict__ idxbuf,
    float* __restrict__ out)
{
    __shared__ float sX[kTPB * kXStride];        // disc, 17.4 KB
    __shared__ unsigned sW[kTPB * kWStride];     // packed idx, 5.1 KB

    const int tid = threadIdx.x;
    const long long rowBase = (long long)blockIdx.x * kTPB;
    const vfloat4* __restrict__ xin4 = (const vfloat4*)(x + rowBase * kRowIn);
    vfloat4* __restrict__ o4 = (vfloat4*)(out + rowBase * kRowOut);

    // packed idx -> LDS (stride 5 uints: conflict-free)
    {
        uint4 v = idxbuf[rowBase + tid];
        unsigned* p = &sW[tid * kWStride];
        p[0] = v.x; p[1] = v.y; p[2] = v.z; p[3] = v.w;
    }
    // disc -> LDS (chunks 0..3 of each row)
#pragma unroll
    for (int i = 0; i < 4; ++i) {
        int flat = i * kTPB + tid;
        int r = flat >> 2, c = flat & 3;
        vfloat4 v = xin4[r * 8 + c];
        float* p = &sX[r * kXStride + c * 4];
        p[0] = v.x; p[1] = v.y; p[2] = v.z; p[3] = v.w;
    }
    __syncthreads();

    // pure coalesced write stream: 100 float4 chunks per row-tile
#pragma unroll 4
    for (int i = 0; i < 100; ++i) {
        unsigned idx = (unsigned)(i * kTPB + tid);   // 0..25599
        unsigned r = idx / 100u;
        unsigned c = idx - r * 100u;
        vfloat4 o;
        if (c < 4u) {
            const float* p = &sX[r * kXStride + c * 4u];
            o.x = p[0]; o.y = p[1]; o.z = p[2]; o.w = p[3];
        } else if (c < 68u) {
            unsigned u = c - 4u, f = u >> 2, q = (u & 3u) * 4u;
            unsigned k = (sW[r * kWStride + (f >> 2)] >> (8u * (f & 3u))) & 15u;
            o.x = (k == q + 0u) ? 1.f : 0.f;
            o.y = (k == q + 1u) ? 1.f : 0.f;
            o.z = (k == q + 2u) ? 1.f : 0.f;
            o.w = (k == q + 3u) ? 1.f : 0.f;
        } else {
            unsigned u = c - 68u, f = u >> 1, q = (u & 1u) * 4u;
            unsigned k = (sW[r * kWStride + (f >> 2)] >> (8u * (f & 3u) + 4u)) & 15u;
            o.x = (k == q + 0u) ? 1.f : 0.f;
            o.y = (k == q + 1u) ? 1.f : 0.f;
            o.z = (k == q + 2u) ? 1.f : 0.f;
            o.w = (k == q + 3u) ? 1.f : 0.f;
        }
        o4[idx] = o;
    }
}

// ======================= fused fallback (r3-proven) =======================
__global__ __launch_bounds__(kTPB) void binlayer_fused(
    const float* __restrict__ x,
    const float* __restrict__ interval,
    const float* __restrict__ interval2,
    const float* __restrict__ i_min,
    float* __restrict__ out,
    double* __restrict__ partial)
{
#pragma clang fp contract(off)
    __shared__ float sC1[kF][kK1];
    __shared__ float sC2[kF][kK2];
    __shared__ float sX[kTPB * 33];
    __shared__ unsigned char sIdx[kTPB * kF];
    __shared__ double sL[kTPB / 64];

    const int tid = threadIdx.x;
    load_centers(interval, interval2, i_min, tid, sC1, sC2);

    const long long rowBase = (long long)blockIdx.x * kTPB;
    const vfloat4* __restrict__ xin4 = (const vfloat4*)(x + rowBase * kRowIn);
#pragma unroll
    for (int i = 0; i < 8; ++i) {
        int flat = i * kTPB + tid;
        vfloat4 v = xin4[flat];
        int r = flat >> 3, c4 = flat & 7;
        float* p = &sX[r * 33 + c4 * 4];
        p[0] = v.x; p[1] = v.y; p[2] = v.z; p[3] = v.w;
    }
    __syncthreads();

    double lacc = 0.0;
    const float* __restrict__ myc = &sX[tid * 33 + 16];
#pragma unroll 1
    for (int f = 0; f < kF; ++f) {
        const float c = myc[f];
        float dd1[kK1];
#pragma unroll
        for (int k = 0; k < kK1; ++k) { float t = c - sC1[f][k]; dd1[k] = t * t; }
        int k1 = soft_argmax_loss<kK1>(dd1, lacc);
        float dd2[kK2];
#pragma unroll
        for (int k = 0; k < kK2; ++k) { float t = c - sC2[f][k]; dd2[k] = t * t; }
        int k2 = soft_argmax_loss<kK2>(dd2, lacc);
        sIdx[tid * kF + f] = (unsigned char)(k1 | (k2 << 4));
    }
#pragma unroll
    for (int off = 32; off > 0; off >>= 1) lacc += __shfl_down(lacc, off);
    if ((tid & 63) == 0) sL[tid >> 6] = lacc;
    __syncthreads();
    if (tid == 0) partial[blockIdx.x] = sL[0] + sL[1] + sL[2] + sL[3];

    vfloat4* __restrict__ o4 = (vfloat4*)(out + rowBase * kRowOut);
#pragma unroll 1
    for (int i = 0; i < 100; ++i) {
        unsigned idx = (unsigned)(i * kTPB + tid);
        unsigned r = idx / 100u;
        unsigned c = idx - r * 100u;
        vfloat4 o;
        if (c < 4u) {
            const float* p = &sX[r * 33 + c * 4u];
            o.x = p[0]; o.y = p[1]; o.z = p[2]; o.w = p[3];
        } else if (c < 68u) {
            unsigned u = c - 4u, f = u >> 2, q = (u & 3u) * 4u;
            unsigned k = sIdx[r * kF + f] & 15u;
            o.x = (k == q + 0u) ? 1.f : 0.f;
            o.y = (k == q + 1u) ? 1.f : 0.f;
            o.z = (k == q + 2u) ? 1.f : 0.f;
            o.w = (k == q + 3u) ? 1.f : 0.f;
        } else {
            unsigned u = c - 68u, f = u >> 1, q = (u & 1u) * 4u;
            unsigned k = (unsigned)(sIdx[r * kF + f]) >> 4;
            o.x = (k == q + 0u) ? 1.f : 0.f;
            o.y = (k == q + 1u) ? 1.f : 0.f;
            o.z = (k == q + 2u) ? 1.f : 0.f;
            o.w = (k == q + 3u) ? 1.f : 0.f;
        }
        o4[idx] = o;
    }
}

__global__ __launch_bounds__(256) void binlayer_finalize(
    const double* __restrict__ partial,
    float* __restrict__ out)
{
    __shared__ double sL[4];
    const int tid = threadIdx.x;
    double s = 0.0;
#pragma unroll
    for (int i = 0; i < kGrid / 256; ++i)
        s += partial[i * 256 + tid];
#pragma unroll
    for (int off = 32; off > 0; off >>= 1) s += __shfl_down(s, off);
    if ((tid & 63) == 0) sL[tid >> 6] = s;
    __syncthreads();
    if (tid == 0)
        out[(long long)kB * kRowOut] =
            (float)((sL[0] + sL[1] + sL[2] + sL[3]) * (1.0 / (double)kB));
}

extern "C" void kernel_launch(void* const* d_in, const int* in_sizes, int n_in,
                              void* d_out, int out_size, void* d_ws, size_t ws_size,
                              hipStream_t stream)
{
    const float* x    = (const float*)d_in[0];
    const float* itv1 = (const float*)d_in[1];
    const float* itv2 = (const float*)d_in[2];
    const float* imin = (const float*)d_in[3];
    float* out = (float*)d_out;

    double* partial = (double*)d_ws;                       // 16 KB
    uint4* idxbuf = (uint4*)((char*)d_ws + kGrid * sizeof(double));
    const size_t need = kGrid * sizeof(double) + (size_t)kB * sizeof(uint4);

    if (ws_size >= need) {
        binlayer_compute<<<kGrid, kTPB, 0, stream>>>(x, itv1, itv2, imin,
                                                     idxbuf, partial);
        binlayer_expand<<<kGrid, kTPB, 0, stream>>>(x, idxbuf, out);
    } else {
        binlayer_fused<<<kGrid, kTPB, 0, stream>>>(x, itv1, itv2, imin,
                                                   out, partial);
    }
    binlayer_finalize<<<1, 256, 0, stream>>>(partial, out);
}

// Round 7
// 953.111 us; speedup vs baseline: 1.0016x; 1.0016x over previous
//
#include <hip/hip_runtime.h>

// BinarizeLayer forward (r7: wave-autonomous fused kernel, based on r3-best).
//   Each wave owns 64 consecutive rows end-to-end in a private LDS region:
//   no block barrier between compute and store (waves decouple; DS pipe is
//   in-order within a wave). Single early __syncthreads only for the shared
//   centers table, placed after global loads are issued into registers.
//   - disc passthrough: direct reg->global copy (full 64B lines, no LDS)
//   - phase 2: row-per-lane, byte-identical math to verified r3 kernel
//   - phase 3: 96 coalesced float4 stores per wave (chunks 4..99)
//   - loss: wave shuffle-reduce -> partial[block*4+wave] (8192 doubles, no memset)
// LDS 23 KB -> 6 blocks/CU (24 waves) vs r3's 4 blocks.

typedef float vfloat4 __attribute__((ext_vector_type(4)));

constexpr int kB      = 524288;
constexpr int kF      = 16;
constexpr int kK1     = 16;
constexpr int kK2     = 8;
constexpr int kRowIn  = 32;    // DISC + F
constexpr int kRowOut = 400;   // DISC + F*K1 + F*K2
constexpr float kEps  = 0.001f;
constexpr int kTPB    = 256;
constexpr int kGrid   = kB / kTPB;       // 2048 blocks
constexpr int kNPart  = kGrid * 4;       // one partial per wave
constexpr int kXStride = 17;             // LDS float row stride (2-way = free)

template <int K>
__device__ __forceinline__ int soft_argmax_loss(const float* __restrict__ dd,
                                                double& lacc)
{
#pragma clang fp contract(off)
    // loss term: sum_k d*softmax(-d); fast exp (output threshold-checked)
    float se = 0.f, sde = 0.f;
#pragma unroll
    for (int k = 0; k < K; ++k) {
        float e = __expf(-dd[k]);
        se += e; sde += dd[k] * e;
    }
    lacc += (double)(sde / se);

    // argmax(softmax(-100*d)) fast path: first-occurrence argmax of z
    float z[K];
#pragma unroll
    for (int k = 0; k < K; ++k) z[k] = -100.0f * dd[k];
    float m = z[0]; int kmax = 0;
#pragma unroll
    for (int k = 1; k < K; ++k) {
        if (z[k] > m) { m = z[k]; kmax = k; }
    }
    // tie-guard: exact expf+IEEE-div replication only if an earlier z is
    // within ~1 ulp of m (exec-masked, ~never taken). Bit-faithful to numpy.
    bool cand = false;
#pragma unroll
    for (int k = 0; k < K; ++k)
        cand |= (k < kmax) & (z[k] >= m - 2.4e-7f);
    if (cand) {
        float e2[K]; float ss = 0.f;
        for (int k = 0; k < K; ++k) { e2[k] = expf(z[k] - m); ss += e2[k]; }
        int km = 0; float pmax = e2[0] / ss;
        for (int k = 1; k < K; ++k) {
            float p = e2[k] / ss;
            if (p > pmax) { pmax = p; km = k; }
        }
        kmax = km;
    }
    return kmax;
}

__global__ __launch_bounds__(kTPB) void binlayer_main(
    const float* __restrict__ x,
    const float* __restrict__ interval,
    const float* __restrict__ interval2,
    const float* __restrict__ i_min,
    float* __restrict__ out,
    double* __restrict__ partial)
{
#pragma clang fp contract(off)
    __shared__ float sC1[kF][kK1];          // 1 KB
    __shared__ float sC2[kF][kK2];          // 0.5 KB
    __shared__ float sCont[4][64 * kXStride]; // 17.4 KB, per-wave regions
    __shared__ unsigned sW[4][64 * 4];        // 4 KB packed idx, per-wave

    const int tid  = threadIdx.x;
    const int wave = tid >> 6;
    const int lane = tid & 63;

    const long long waveRow = (long long)blockIdx.x * kTPB + wave * 64;
    const vfloat4* __restrict__ xin4 = (const vfloat4*)(x + waveRow * kRowIn);
    vfloat4* __restrict__ o4 = (vfloat4*)(out + waveRow * kRowOut);

    // ---- issue cont loads into registers (latency hides across the barrier) ----
    vfloat4 cv[4];
#pragma unroll
    for (int i = 0; i < 4; ++i) {
        int flat = i * 64 + lane;            // 0..255
        int r = flat >> 2, c = flat & 3;
        cv[i] = xin4[r * 8 + 4 + c];
    }
    // ---- disc passthrough: reg->global, whole 64B lines, no LDS ----
#pragma unroll
    for (int i = 0; i < 4; ++i) {
        int flat = i * 64 + lane;
        int r = flat >> 2, c = flat & 3;
        o4[r * 100 + c] = xin4[r * 8 + c];
    }

    // ---- centers: i_min + fp32 cumsum of max(interval, eps) ----
    if (tid < kF) {
        const float base = i_min[tid];
        float run = 0.f;
        for (int k = 0; k < kK1; ++k) {
            run += fmaxf(interval[tid * kK1 + k], kEps);
            sC1[tid][k] = base + run;
        }
        run = 0.f;
        for (int k = 0; k < kK2; ++k) {
            run += fmaxf(interval2[tid * kK2 + k], kEps);
            sC2[tid][k] = base + run;
        }
    }
    __syncthreads();   // the ONLY block barrier (centers visibility)

    // ---- cont regs -> wave-private LDS ----
    float* __restrict__ wc = sCont[wave];
#pragma unroll
    for (int i = 0; i < 4; ++i) {
        int flat = i * 64 + lane;
        int r = flat >> 2, c = flat & 3;
        float* p = &wc[r * kXStride + c * 4];
        p[0] = cv[i].x; p[1] = cv[i].y; p[2] = cv[i].z; p[3] = cv[i].w;
    }

    // ---- phase 2: row = lane (math identical to verified r3) ----
    double lacc = 0.0;
    const float* __restrict__ myc = &wc[lane * kXStride];
    unsigned w[4] = {0u, 0u, 0u, 0u};

#pragma unroll 1
    for (int f = 0; f < kF; ++f) {
        const float c = myc[f];
        float dd1[kK1];
#pragma unroll
        for (int k = 0; k < kK1; ++k) { float t = c - sC1[f][k]; dd1[k] = t * t; }
        int k1 = soft_argmax_loss<kK1>(dd1, lacc);
        float dd2[kK2];
#pragma unroll
        for (int k = 0; k < kK2; ++k) { float t = c - sC2[f][k]; dd2[k] = t * t; }
        int k2 = soft_argmax_loss<kK2>(dd2, lacc);
        w[f >> 2] |= (unsigned)(k1 | (k2 << 4)) << (8 * (f & 3));
    }
    {
        unsigned* p = &sW[wave][lane * 4];
        p[0] = w[0]; p[1] = w[1]; p[2] = w[2]; p[3] = w[3];
    }

    // loss: wave shuffle-reduce -> one double store per wave (no LDS, no atomics)
#pragma unroll
    for (int off = 32; off > 0; off >>= 1) lacc += __shfl_down(lacc, off);
    if (lane == 0) partial[blockIdx.x * 4 + wave] = lacc;

    // ---- phase 3: wave-local coalesced store stream, chunks 4..99 ----
    // DS pipe is in-order within a wave: sW writes above are visible to the
    // reads below without any barrier.
    const unsigned* __restrict__ ww = sW[wave];
#pragma unroll 4
    for (int i = 0; i < 96; ++i) {
        unsigned idx = (unsigned)(i * 64 + lane);    // 0..6143
        unsigned r = idx / 96u;                      // wave-local row 0..63
        unsigned c = idx - r * 96u;                  // 0..95 -> chunk 4+c
        vfloat4 o;
        if (c < 64u) {
            unsigned f = c >> 2, q = (c & 3u) * 4u;
            unsigned k = (ww[r * 4u + (f >> 2)] >> (8u * (f & 3u))) & 15u;
            o.x = (k == q + 0u) ? 1.f : 0.f;
            o.y = (k == q + 1u) ? 1.f : 0.f;
            o.z = (k == q + 2u) ? 1.f : 0.f;
            o.w = (k == q + 3u) ? 1.f : 0.f;
        } else {
            unsigned u = c - 64u, f = u >> 1, q = (u & 1u) * 4u;
            unsigned k = (ww[r * 4u + (f >> 2)] >> (8u * (f & 3u) + 4u)) & 15u;
            o.x = (k == q + 0u) ? 1.f : 0.f;
            o.y = (k == q + 1u) ? 1.f : 0.f;
            o.z = (k == q + 2u) ? 1.f : 0.f;
            o.w = (k == q + 3u) ? 1.f : 0.f;
        }
        o4[r * 100u + 4u + c] = o;
    }
}

__global__ __launch_bounds__(256) void binlayer_finalize(
    const double* __restrict__ partial,
    float* __restrict__ out)
{
    __shared__ double sL[4];
    const int tid = threadIdx.x;
    double s = 0.0;
#pragma unroll
    for (int i = 0; i < kNPart / 256; ++i)       // 32 values each
        s += partial[i * 256 + tid];
#pragma unroll
    for (int off = 32; off > 0; off >>= 1) s += __shfl_down(s, off);
    if ((tid & 63) == 0) sL[tid >> 6] = s;
    __syncthreads();
    if (tid == 0)
        out[(long long)kB * kRowOut] =
            (float)((sL[0] + sL[1] + sL[2] + sL[3]) * (1.0 / (double)kB));
}

extern "C" void kernel_launch(void* const* d_in, const int* in_sizes, int n_in,
                              void* d_out, int out_size, void* d_ws, size_t ws_size,
                              hipStream_t stream)
{
    const float* x    = (const float*)d_in[0];
    const float* itv1 = (const float*)d_in[1];
    const float* itv2 = (const float*)d_in[2];
    const float* imin = (const float*)d_in[3];
    float* out = (float*)d_out;
    double* partial = (double*)d_ws;   // kNPart doubles = 64 KB, fully overwritten

    binlayer_main<<<kGrid, kTPB, 0, stream>>>(x, itv1, itv2, imin, out, partial);
    binlayer_finalize<<<1, 256, 0, stream>>>(partial, out);
}